// Round 4
// baseline (623.415 us; speedup 1.0000x reference)
//
#include <hip/hip_runtime.h>
#include <hip/hip_bf16.h>
#include <math.h>

// Problem constants (match reference setup_inputs)
#define NN   100000
#define NE   1600000
#define FIN  128
#define HID  32
#define NHEADS 4
#define NCLS 10

typedef unsigned int uint32;
typedef __fp16 half2_t __attribute__((ext_vector_type(2)));
typedef __fp16 half8_t __attribute__((ext_vector_type(8)));
typedef float  f32x4   __attribute__((ext_vector_type(4)));

// pack 2 fp32 -> packed fp16 pair (v_cvt_pkrtz_f16_f32, 1 inst)
__device__ __forceinline__ uint32 packh2(float a, float b) {
    half2_t h = __builtin_amdgcn_cvt_pkrtz(a, b);
    return __builtin_bit_cast(uint32, h);
}
__device__ __forceinline__ float h_lo(uint32 v) {
    return (float)__builtin_bit_cast(half2_t, v)[0];
}
__device__ __forceinline__ float h_hi(uint32 v) {
    return (float)__builtin_bit_cast(half2_t, v)[1];
}
__device__ __forceinline__ half8_t as_h8(uint4 v) {
    return __builtin_bit_cast(half8_t, v);
}

// ---------------------------------------------------------------------------
// setup: zero cnt + conv_w (W fp32 -> packed fp16 transposed) + bn fold.
// All independent elementwise work fused into one launch (391 blocks).
//   conv_w: Wt[n][k/2] packed; bn: A=g*rsqrt(v+eps), B=bt+(b-m)*A
//   bn layer offsets in A/B: l0 0..127, l1 128..255, l2 256..287
// ---------------------------------------------------------------------------
__global__ __launch_bounds__(256) void setup_kernel(
    int* __restrict__ cnt, int n,
    const float* __restrict__ W0, const float* __restrict__ W1,
    const float* __restrict__ W2, uint32* __restrict__ Wt0,
    uint32* __restrict__ Wt1, uint32* __restrict__ Wt2,
    const float* __restrict__ b0, const float* __restrict__ g0, const float* __restrict__ bt0,
    const float* __restrict__ m0, const float* __restrict__ v0,
    const float* __restrict__ b1, const float* __restrict__ g1, const float* __restrict__ bt1,
    const float* __restrict__ m1, const float* __restrict__ v1,
    const float* __restrict__ b2, const float* __restrict__ g2, const float* __restrict__ bt2,
    const float* __restrict__ m2, const float* __restrict__ v2,
    float* __restrict__ A, float* __restrict__ B) {
    const int t = blockIdx.x * 256 + threadIdx.x;
    if (t < n) cnt[t] = 0;
    if (t < 8192) {
        const int nn = t >> 6, ku = t & 63;
        Wt0[t] = packh2(W0[(2 * ku) * 128 + nn], W0[(2 * ku + 1) * 128 + nn]);
    } else if (t < 16384) {
        const int l = t - 8192;
        const int nn = l >> 6, ku = l & 63;
        Wt1[l] = packh2(W1[(2 * ku) * 128 + nn], W1[(2 * ku + 1) * 128 + nn]);
    } else if (t < 18432) {
        const int l = t - 16384;
        const int nn = l >> 6, ku = l & 63;
        Wt2[l] = packh2(W2[(2 * ku) * 32 + nn], W2[(2 * ku + 1) * 32 + nn]);
    } else if (t < 18432 + 288) {
        const int u = t - 18432;
        const float *b, *g, *bt, *m, *v;
        int c;
        if (u < 128)      { b = b0; g = g0; bt = bt0; m = m0; v = v0; c = u; }
        else if (u < 256) { b = b1; g = g1; bt = bt1; m = m1; v = v1; c = u - 128; }
        else              { b = b2; g = g2; bt = bt2; m = m2; v = v2; c = u - 256; }
        const float s = g[c] * rsqrtf(v[c] + 1e-5f);
        A[u] = s;
        B[u] = bt[c] + (b[c] - m[c]) * s;
    }
}

// ---------------------------------------------------------------------------
// CSR build: histogram (atomics only; rank array eliminated — scatter claims
// slots via atomicAdd on wptr, order within a destination is irrelevant)
// ---------------------------------------------------------------------------
__global__ void hist_kernel(const int* __restrict__ dst, int* __restrict__ cnt, int e) {
    const int t0 = blockIdx.x * (blockDim.x * 4) + threadIdx.x;
#pragma unroll
    for (int k = 0; k < 4; ++k) {
        const int j = t0 + k * 256;
        if (j < e) atomicAdd(&cnt[dst[j]], 1);
    }
}

__global__ void scan_block_sums(const int* __restrict__ cnt, int* __restrict__ bsum, int n) {
    __shared__ int sm[256];
    int i = blockIdx.x * 256 + threadIdx.x;
    int v = (i < n) ? cnt[i] : 0;
    sm[threadIdx.x] = v;
    __syncthreads();
    for (int off = 128; off > 0; off >>= 1) {
        if (threadIdx.x < off) sm[threadIdx.x] += sm[threadIdx.x + off];
        __syncthreads();
    }
    if (threadIdx.x == 0) bsum[blockIdx.x] = sm[0];
}

// scan_final + inline block-prefix (fuses old scan_single): each block reduces
// bsum[0..blockIdx) itself (<=512 ints, L2-broadcast), then local scans cnt.
// Writes rowptr AND wptr (scatter's atomic write cursor copy).
__global__ void scan_final(const int* __restrict__ cnt, const int* __restrict__ bsum,
                           int* __restrict__ rowptr, int* __restrict__ wptr, int n) {
    __shared__ int sm[256];
    const int b = blockIdx.x;
    const int t = threadIdx.x;
    // --- block prefix: sum of bsum[i], i < b
    int s = 0;
    for (int i = t; i < b; i += 256) s += bsum[i];
    sm[t] = s;
    __syncthreads();
    for (int off = 128; off > 0; off >>= 1) {
        if (t < off) sm[t] += sm[t + off];
        __syncthreads();
    }
    const int boff = sm[0];
    __syncthreads();
    // --- local inclusive scan of cnt
    const int i = b * 256 + t;
    const int v = (i < n) ? cnt[i] : 0;
    sm[t] = v;
    __syncthreads();
    for (int off = 1; off < 256; off <<= 1) {
        int u = (t >= off) ? sm[t - off] : 0;
        __syncthreads();
        sm[t] += u;
        __syncthreads();
    }
    const int incl = sm[t];
    const int excl = incl - v;
    if (i < n) {
        rowptr[i] = boff + excl;
        wptr[i]   = boff + excl;
    }
    if (i == n - 1) rowptr[n] = boff + incl;  // == E
}

__global__ void scatter_kernel(const int* __restrict__ src, const int* __restrict__ dst,
                               int* __restrict__ wptr, int* __restrict__ esrc, int e) {
    const int t0 = blockIdx.x * (blockDim.x * 4) + threadIdx.x;
#pragma unroll
    for (int k = 0; k < 4; ++k) {
        const int j = t0 + k * 256;
        if (j < e) {
            const int d = dst[j];
            const int s = src[j];
            const int pos = atomicAdd(&wptr[d], 1);
            // nt store: avoid 128B write-allocate fetch per scattered 4B store
            __builtin_nontemporal_store(s, &esrc[pos]);
        }
    }
}

// ---------------------------------------------------------------------------
// MFMA GEMM (fp16 in, fp32 acc) + fused attention-logit epilogue.
// CONVA=true: A source is fp32 x, converted in-register (fuses conv_x;
// identical numerics: same cvt_pkrtz).
// ---------------------------------------------------------------------------
template <int FOUT, int H, bool CONVA>
__global__ __launch_bounds__(256) void gemm_mfma(const void* __restrict__ Xv,
                                                 const uint32* __restrict__ Wt,
                                                 const float* __restrict__ a_s,
                                                 const float* __restrict__ a_d,
                                                 float* __restrict__ alS,
                                                 float* __restrict__ alD,
                                                 uint32* __restrict__ Outh, int n) {
    constexpr int NT = FOUT / 16;            // 8 or 2 n-tiles
    const int wave = threadIdx.x >> 6;
    const int lane = threadIdx.x & 63;
    const int c = lane & 15;                 // D col / A load row / B col
    const int q = lane >> 4;                 // quad
    const int row0 = blockIdx.x * 128 + wave * 32;

    int r0 = row0 + c;
    int r1 = row0 + 16 + c;
    if (r0 >= n) r0 = n - 1;
    if (r1 >= n) r1 = n - 1;

    f32x4 acc[2][NT];
#pragma unroll
    for (int m = 0; m < 2; ++m)
#pragma unroll
        for (int nt = 0; nt < NT; ++nt) acc[m][nt] = (f32x4){0.f, 0.f, 0.f, 0.f};

    const uint4*  XU = (const uint4*)Xv;
    const float4* XF = (const float4*)Xv;
    const uint4*  WU = (const uint4*)Wt;

#pragma unroll
    for (int ks = 0; ks < 4; ++ks) {
        half8_t a0, a1;
        if constexpr (CONVA) {
            const float4 f0 = XF[(size_t)r0 * 32 + (ks * 4 + q) * 2];
            const float4 f1 = XF[(size_t)r0 * 32 + (ks * 4 + q) * 2 + 1];
            a0 = as_h8(make_uint4(packh2(f0.x, f0.y), packh2(f0.z, f0.w),
                                  packh2(f1.x, f1.y), packh2(f1.z, f1.w)));
            const float4 g0 = XF[(size_t)r1 * 32 + (ks * 4 + q) * 2];
            const float4 g1 = XF[(size_t)r1 * 32 + (ks * 4 + q) * 2 + 1];
            a1 = as_h8(make_uint4(packh2(g0.x, g0.y), packh2(g0.z, g0.w),
                                  packh2(g1.x, g1.y), packh2(g1.z, g1.w)));
        } else {
            a0 = as_h8(XU[(size_t)r0 * 16 + ks * 4 + q]);
            a1 = as_h8(XU[(size_t)r1 * 16 + ks * 4 + q]);
        }
#pragma unroll
        for (int nt = 0; nt < NT; ++nt) {
            const half8_t b = as_h8(WU[(nt * 16 + c) * 16 + ks * 4 + q]);
            acc[0][nt] = __builtin_amdgcn_mfma_f32_16x16x32_f16(a0, b, acc[0][nt], 0, 0, 0);
            acc[1][nt] = __builtin_amdgcn_mfma_f32_16x16x32_f16(a1, b, acc[1][nt], 0, 0, 0);
        }
    }

    // a_s/a_d values for my columns (flat [H*C] == flat col index)
    float asv[NT], adv[NT];
#pragma unroll
    for (int nt = 0; nt < NT; ++nt) {
        asv[nt] = a_s[c + 16 * nt];
        adv[nt] = a_d[c + 16 * nt];
    }

#pragma unroll
    for (int m = 0; m < 2; ++m) {
#pragma unroll
        for (int reg = 0; reg < 4; ++reg) {
            const int grow = row0 + m * 16 + q * 4 + reg;
            const bool ok = (grow < n);
            // ---- fused logits: per-head partial dot, reduce over 16-lane row group
            if constexpr (H == 4) {
                float ps[4], pd[4];
#pragma unroll
                for (int h = 0; h < 4; ++h) {
                    ps[h] = acc[m][2 * h][reg] * asv[2 * h] + acc[m][2 * h + 1][reg] * asv[2 * h + 1];
                    pd[h] = acc[m][2 * h][reg] * adv[2 * h] + acc[m][2 * h + 1][reg] * adv[2 * h + 1];
                }
#pragma unroll
                for (int off = 1; off < 16; off <<= 1) {
#pragma unroll
                    for (int h = 0; h < 4; ++h) {
                        ps[h] += __shfl_xor(ps[h], off);
                        pd[h] += __shfl_xor(pd[h], off);
                    }
                }
                if (c < 4 && ok) {
                    const float vs = (c == 0) ? ps[0] : (c == 1) ? ps[1] : (c == 2) ? ps[2] : ps[3];
                    const float vd = (c == 0) ? pd[0] : (c == 1) ? pd[1] : (c == 2) ? pd[2] : pd[3];
                    alS[(size_t)grow * 4 + c] = vs;
                    alD[(size_t)grow * 4 + c] = vd;
                }
            } else {
                float ps = acc[m][0][reg] * asv[0] + acc[m][1][reg] * asv[1];
                float pd = acc[m][0][reg] * adv[0] + acc[m][1][reg] * adv[1];
#pragma unroll
                for (int off = 1; off < 16; off <<= 1) {
                    ps += __shfl_xor(ps, off);
                    pd += __shfl_xor(pd, off);
                }
                if (c == 0 && ok) {
                    alS[grow] = ps;
                    alD[grow] = pd;
                }
            }
            // ---- fp16-packed C store: pair col c with c^1, even lanes write
#pragma unroll
            for (int nt = 0; nt < NT; ++nt) {
                const float v = acc[m][nt][reg];
                const float o = __shfl_xor(v, 1);
                if (((c & 1) == 0) && ok) {
                    Outh[(size_t)grow * (FOUT / 2) + nt * 8 + (c >> 1)] = packh2(v, o);
                }
            }
        }
    }
}

// ---------------------------------------------------------------------------
// wave-per-destination aggregation, single-phase / zero-LDS.
//   B16[d][F/2] = fp16( elu( (sum_e softmax(e)_e * h[src_e,:]) * A + B ) )
// Lane split: li = lane & (RU4-1) owns one uint4 (8 fp16 channels) of the row;
//             g  = lane / RU4 owns an edge slot.
// All loads cached (no nt: Hb/alS retention in L2 is the perf story; esrc and
// B16 are re-read by subsequent kernels).
// NOTE: grid must be ceil(n/4); 4 destinations (waves) per block.
// ---------------------------------------------------------------------------
template <int H, int C>
__global__ __launch_bounds__(256) void gat_aggregate(
    const uint32* __restrict__ Hb,            // fp16-packed h, row = H*C/2 uints
    const int* __restrict__ rowptr, const int* __restrict__ esrc,
    const float* __restrict__ alS, const float* __restrict__ alD,
    const float* __restrict__ bnA, const float* __restrict__ bnB,
    uint32* __restrict__ B16, int n) {
    constexpr int F    = H * C;               // 128 or 32
    constexpr int RU4  = F / 8;               // uint4 per row: 16 or 4
    constexpr int SLOTS = 64 / RU4;           // edge slots: 4 or 16
    constexpr int UNROLL = 16 / SLOTS;        // 4 or 1  (16 edges per step)

    const int wave = threadIdx.x >> 6;
    const int lane = threadIdx.x & 63;
    int d = blockIdx.x * 4 + wave;
    if (d >= n) return;
    d = __builtin_amdgcn_readfirstlane(d);    // wave-uniform -> scalar addressing

    const int li = lane & (RU4 - 1);          // row quarter (8 channels: 8li..8li+7)
    const int g  = lane / RU4;                // edge slot
    const int head = (H == 4) ? (li >> 2) : 0;

    const float ald = alD[(size_t)d * H + head];
    const int beg = rowptr[d];
    const int end = rowptr[d + 1];
    const int endm1 = end - 1;

    float acc[8];
#pragma unroll
    for (int k = 0; k < 8; ++k) acc[k] = 0.f;
    float den = 0.f;

    const uint4* HbU4 = (const uint4*)Hb;

    for (int base = beg; base < end; base += 16) {
#pragma unroll
        for (int u = 0; u < UNROLL; ++u) {
            const int j  = base + u * SLOTS + g;
            const bool act = (j < end);
            const int jc = act ? j : endm1;          // clamp: stay in-bounds
            const int sj = esrc[jc];
            const float aw = (H == 4) ? alS[(size_t)sj * 4 + head] : alS[sj];
            float t = aw + ald;
            t = fmaxf(t, 0.2f * t);                  // leaky relu (slope 0.2)
            const float ex = act ? __expf(t) : 0.f;  // bounded logits: no max-sub
            den += ex;
            const uint4 v = HbU4[(size_t)sj * RU4 + li];
            acc[0] = fmaf(h_lo(v.x), ex, acc[0]);
            acc[1] = fmaf(h_hi(v.x), ex, acc[1]);
            acc[2] = fmaf(h_lo(v.y), ex, acc[2]);
            acc[3] = fmaf(h_hi(v.y), ex, acc[3]);
            acc[4] = fmaf(h_lo(v.z), ex, acc[4]);
            acc[5] = fmaf(h_hi(v.z), ex, acc[5]);
            acc[6] = fmaf(h_lo(v.w), ex, acc[6]);
            acc[7] = fmaf(h_hi(v.w), ex, acc[7]);
        }
    }

    // reduce across edge slots (xor over the g bits; li preserved)
#pragma unroll
    for (int off = RU4; off < 64; off <<= 1) {
#pragma unroll
        for (int k = 0; k < 8; ++k) acc[k] += __shfl_xor(acc[k], off);
        den += __shfl_xor(den, off);
    }

    if (lane < RU4) {
        const float inv = 1.f / (den + 1e-16f);
        const int c0 = 8 * li;
        const float4 A0 = *(const float4*)(bnA + c0);
        const float4 A1 = *(const float4*)(bnA + c0 + 4);
        const float4 B0 = *(const float4*)(bnB + c0);
        const float4 B1 = *(const float4*)(bnB + c0 + 4);
        const float As[8] = {A0.x, A0.y, A0.z, A0.w, A1.x, A1.y, A1.z, A1.w};
        const float Bs[8] = {B0.x, B0.y, B0.z, B0.w, B1.x, B1.y, B1.z, B1.w};
        float y[8];
#pragma unroll
        for (int k = 0; k < 8; ++k) {
            const float yy = acc[k] * inv * As[k] + Bs[k];
            y[k] = yy > 0.f ? yy : expm1f(yy);       // ELU
        }
        uint4 o;
        o.x = packh2(y[0], y[1]);
        o.y = packh2(y[2], y[3]);
        o.z = packh2(y[4], y[5]);
        o.w = packh2(y[6], y[7]);
        ((uint4*)B16)[(size_t)d * RU4 + li] = o;
    }
}

// ---------------------------------------------------------------------------
// classifier: out[n, 10] = fp16(H3)[n, 32] @ Wc[32, 10] + bc
// thread-per-node: row loaded once.
// ---------------------------------------------------------------------------
__global__ __launch_bounds__(256) void classifier_kernel(
    const uint32* __restrict__ H3, const float* __restrict__ Wc,
    const float* __restrict__ bc, float* __restrict__ out, int n) {
    const int ni = blockIdx.x * blockDim.x + threadIdx.x;
    if (ni >= n) return;
    const uint4* row = (const uint4*)(H3 + (size_t)ni * 16);
    float xf[32];
#pragma unroll
    for (int u = 0; u < 4; ++u) {
        const uint4 v = row[u];
        xf[u * 8 + 0] = h_lo(v.x); xf[u * 8 + 1] = h_hi(v.x);
        xf[u * 8 + 2] = h_lo(v.y); xf[u * 8 + 3] = h_hi(v.y);
        xf[u * 8 + 4] = h_lo(v.z); xf[u * 8 + 5] = h_hi(v.z);
        xf[u * 8 + 6] = h_lo(v.w); xf[u * 8 + 7] = h_hi(v.w);
    }
    float o[NCLS];
#pragma unroll
    for (int c = 0; c < NCLS; ++c) o[c] = bc[c];
#pragma unroll
    for (int u = 0; u < 32; ++u) {
#pragma unroll
        for (int c = 0; c < NCLS; ++c) o[c] = fmaf(xf[u], Wc[u * NCLS + c], o[c]);
    }
    float* orow = out + (size_t)ni * NCLS;
#pragma unroll
    for (int c = 0; c < NCLS; c += 2) {
        *(float2*)(orow + c) = make_float2(o[c], o[c + 1]);
    }
}

// ---------------------------------------------------------------------------
// launch
// ---------------------------------------------------------------------------
static inline char* align256(char* p) {
    return (char*)(((uintptr_t)p + 255) & ~(uintptr_t)255);
}

extern "C" void kernel_launch(void* const* d_in, const int* in_sizes, int n_in,
                              void* d_out, int out_size, void* d_ws, size_t ws_size,
                              hipStream_t stream) {
    const float* x  = (const float*)d_in[0];
    const int*   ei = (const int*)d_in[1];
    const int N = in_sizes[0] / FIN;
    const int E = in_sizes[1] / 2;
    const int* src = ei;
    const int* dst = ei + E;

    const float *W0 = (const float*)d_in[2],  *as0 = (const float*)d_in[3],
                *ad0 = (const float*)d_in[4], *b0 = (const float*)d_in[5],
                *g0 = (const float*)d_in[6],  *bt0 = (const float*)d_in[7],
                *m0 = (const float*)d_in[8],  *v0 = (const float*)d_in[9];
    const float *W1 = (const float*)d_in[10], *as1 = (const float*)d_in[11],
                *ad1 = (const float*)d_in[12],*b1 = (const float*)d_in[13],
                *g1 = (const float*)d_in[14], *bt1 = (const float*)d_in[15],
                *m1 = (const float*)d_in[16], *v1 = (const float*)d_in[17];
    const float *W2 = (const float*)d_in[18], *as2 = (const float*)d_in[19],
                *ad2 = (const float*)d_in[20],*b2 = (const float*)d_in[21],
                *g2 = (const float*)d_in[22], *bt2 = (const float*)d_in[23],
                *m2 = (const float*)d_in[24], *v2 = (const float*)d_in[25];
    const float *Wc = (const float*)d_in[26], *bc = (const float*)d_in[27];
    float* out = (float*)d_out;

    // workspace carve
    char* p = (char*)d_ws;
    uint32* Ht  = (uint32*)p;   p = align256(p + (size_t)N * 64 * 4);    // gemm out fp16
    uint32* B16 = (uint32*)p;   p = align256(p + (size_t)N * 64 * 4);    // layer act fp16
    uint32* Wt0 = (uint32*)p;   p = align256(p + 8192 * 4);
    uint32* Wt1 = (uint32*)p;   p = align256(p + 8192 * 4);
    uint32* Wt2 = (uint32*)p;   p = align256(p + 2048 * 4);
    float* alS = (float*)p;     p = align256(p + (size_t)N * NHEADS * 4);
    float* alD = (float*)p;     p = align256(p + (size_t)N * NHEADS * 4);
    int* cnt = (int*)p;         p = align256(p + (size_t)N * 4);
    int* rowptr = (int*)p;      p = align256(p + (size_t)(N + 1) * 4);
    int* wptr = (int*)p;        p = align256(p + (size_t)N * 4);
    int* esrc = (int*)p;        p = align256(p + (size_t)E * 4);
    int* bsum = (int*)p;        p = align256(p + 512 * 4);
    float* bnA = (float*)p;     p = align256(p + 288 * 4);
    float* bnB = (float*)p;     p = align256(p + 288 * 4);
    (void)ws_size; (void)n_in; (void)out_size;

    const int NB = (N + 255) / 256;
    const int EB4 = (E + 1023) / 1024;   // 4 edges/thread kernels

    // ---- setup (zero cnt + weight conversion + BN fold, one launch) ----
    setup_kernel<<<NB, 256, 0, stream>>>(cnt, N, W0, W1, W2, Wt0, Wt1, Wt2,
                                         b0, g0, bt0, m0, v0,
                                         b1, g1, bt1, m1, v1,
                                         b2, g2, bt2, m2, v2, bnA, bnB);

    // ---- CSR build (once; shared by all 3 layers) ----
    hist_kernel<<<EB4, 256, 0, stream>>>(dst, cnt, E);
    scan_block_sums<<<NB, 256, 0, stream>>>(cnt, bsum, N);
    scan_final<<<NB, 256, 0, stream>>>(cnt, bsum, rowptr, wptr, N);
    scatter_kernel<<<EB4, 256, 0, stream>>>(src, dst, wptr, esrc, E);

    const int GB = (N + 127) / 128;
    const int AB = (N + 3) / 4;          // aggregate blocks: 4 dst per block

    // ---- layer 0 (fp32 x converted in-register in the GEMM A-path) ----
    gemm_mfma<128, 4, true><<<GB, 256, 0, stream>>>(x, Wt0, as0, ad0, alS, alD, Ht, N);
    gat_aggregate<4, 32><<<AB, 256, 0, stream>>>(Ht, rowptr, esrc, alS, alD,
                                                 bnA, bnB, B16, N);
    // ---- layer 1 ----
    gemm_mfma<128, 4, false><<<GB, 256, 0, stream>>>(B16, Wt1, as1, ad1, alS, alD, Ht, N);
    gat_aggregate<4, 32><<<AB, 256, 0, stream>>>(Ht, rowptr, esrc, alS, alD,
                                                 bnA + 128, bnB + 128, B16, N);
    // ---- layer 2 (single head, C=32) ----
    gemm_mfma<32, 1, false><<<GB, 256, 0, stream>>>(B16, Wt2, as2, ad2, alS, alD, Ht, N);
    gat_aggregate<1, 32><<<AB, 256, 0, stream>>>(Ht, rowptr, esrc, alS, alD,
                                                 bnA + 256, bnB + 256, B16, N);
    // ---- classifier ----
    classifier_kernel<<<(N + 255) / 256, 256, 0, stream>>>(B16, Wc, bc, out, N);
}

// Round 5
// 512.709 us; speedup vs baseline: 1.2159x; 1.2159x over previous
//
#include <hip/hip_runtime.h>
#include <hip/hip_bf16.h>
#include <math.h>

// Problem constants (match reference setup_inputs)
#define NN   100000
#define NE   1600000
#define FIN  128
#define HID  32
#define NHEADS 4
#define NCLS 10

typedef unsigned int uint32;
typedef __fp16 half2_t __attribute__((ext_vector_type(2)));
typedef __fp16 half8_t __attribute__((ext_vector_type(8)));
typedef float  f32x4   __attribute__((ext_vector_type(4)));

// pack 2 fp32 -> packed fp16 pair (v_cvt_pkrtz_f16_f32, 1 inst)
__device__ __forceinline__ uint32 packh2(float a, float b) {
    half2_t h = __builtin_amdgcn_cvt_pkrtz(a, b);
    return __builtin_bit_cast(uint32, h);
}
__device__ __forceinline__ float h_lo(uint32 v) {
    return (float)__builtin_bit_cast(half2_t, v)[0];
}
__device__ __forceinline__ float h_hi(uint32 v) {
    return (float)__builtin_bit_cast(half2_t, v)[1];
}
__device__ __forceinline__ half8_t as_h8(uint4 v) {
    return __builtin_bit_cast(half8_t, v);
}

// ---------------------------------------------------------------------------
// setup: zero cnt + conv_w (W fp32 -> packed fp16 transposed) + bn fold.
// All independent elementwise work fused into one launch.
//   conv_w: Wt[n][k/2] packed; bn: A=g*rsqrt(v+eps), B=bt+(b-m)*A
//   bn layer offsets in A/B: l0 0..127, l1 128..255, l2 256..287
// ---------------------------------------------------------------------------
__global__ __launch_bounds__(256) void setup_kernel(
    int* __restrict__ cnt, int n,
    const float* __restrict__ W0, const float* __restrict__ W1,
    const float* __restrict__ W2, uint32* __restrict__ Wt0,
    uint32* __restrict__ Wt1, uint32* __restrict__ Wt2,
    const float* __restrict__ b0, const float* __restrict__ g0, const float* __restrict__ bt0,
    const float* __restrict__ m0, const float* __restrict__ v0,
    const float* __restrict__ b1, const float* __restrict__ g1, const float* __restrict__ bt1,
    const float* __restrict__ m1, const float* __restrict__ v1,
    const float* __restrict__ b2, const float* __restrict__ g2, const float* __restrict__ bt2,
    const float* __restrict__ m2, const float* __restrict__ v2,
    float* __restrict__ A, float* __restrict__ B) {
    const int t = blockIdx.x * 256 + threadIdx.x;
    if (t < n) cnt[t] = 0;
    if (t < 8192) {
        const int nn = t >> 6, ku = t & 63;
        Wt0[t] = packh2(W0[(2 * ku) * 128 + nn], W0[(2 * ku + 1) * 128 + nn]);
    } else if (t < 16384) {
        const int l = t - 8192;
        const int nn = l >> 6, ku = l & 63;
        Wt1[l] = packh2(W1[(2 * ku) * 128 + nn], W1[(2 * ku + 1) * 128 + nn]);
    } else if (t < 18432) {
        const int l = t - 16384;
        const int nn = l >> 6, ku = l & 63;
        Wt2[l] = packh2(W2[(2 * ku) * 32 + nn], W2[(2 * ku + 1) * 32 + nn]);
    } else if (t < 18432 + 288) {
        const int u = t - 18432;
        const float *b, *g, *bt, *m, *v;
        int c;
        if (u < 128)      { b = b0; g = g0; bt = bt0; m = m0; v = v0; c = u; }
        else if (u < 256) { b = b1; g = g1; bt = bt1; m = m1; v = v1; c = u - 128; }
        else              { b = b2; g = g2; bt = bt2; m = m2; v = v2; c = u - 256; }
        const float s = g[c] * rsqrtf(v[c] + 1e-5f);
        A[u] = s;
        B[u] = bt[c] + (b[c] - m[c]) * s;
    }
}

// ---------------------------------------------------------------------------
// CSR build: histogram with returned rank (atomics concentrated here; scatter
// is then atomic-free with naturally L2-coalescing stores). Plain cached
// accesses throughout — nt hints measured harmful on this chip (R3/R4).
// ---------------------------------------------------------------------------
__global__ void hist_rank_kernel(const int* __restrict__ dst, int* __restrict__ cnt,
                                 int* __restrict__ rank, int e) {
    const int t0 = blockIdx.x * (blockDim.x * 4) + threadIdx.x;
    int d[4];
    bool a[4];
#pragma unroll
    for (int k = 0; k < 4; ++k) {
        const int j = t0 + k * 256;
        a[k] = (j < e);
        d[k] = a[k] ? dst[j] : 0;
    }
    int r[4];
#pragma unroll
    for (int k = 0; k < 4; ++k)
        if (a[k]) r[k] = atomicAdd(&cnt[d[k]], 1);
#pragma unroll
    for (int k = 0; k < 4; ++k) {
        const int j = t0 + k * 256;
        if (a[k]) rank[j] = r[k];
    }
}

__global__ void scan_block_sums(const int* __restrict__ cnt, int* __restrict__ bsum, int n) {
    __shared__ int sm[256];
    int i = blockIdx.x * 256 + threadIdx.x;
    int v = (i < n) ? cnt[i] : 0;
    sm[threadIdx.x] = v;
    __syncthreads();
    for (int off = 128; off > 0; off >>= 1) {
        if (threadIdx.x < off) sm[threadIdx.x] += sm[threadIdx.x + off];
        __syncthreads();
    }
    if (threadIdx.x == 0) bsum[blockIdx.x] = sm[0];
}

// scan_final with inline block-prefix (fuses old scan_single): each block
// reduces bsum[0..blockIdx) itself (<=391 ints, L2-broadcast), then local
// scans cnt to produce rowptr.
__global__ void scan_final(const int* __restrict__ cnt, const int* __restrict__ bsum,
                           int* __restrict__ rowptr, int n) {
    __shared__ int sm[256];
    const int b = blockIdx.x;
    const int t = threadIdx.x;
    // --- block prefix: sum of bsum[i], i < b
    int s = 0;
    for (int i = t; i < b; i += 256) s += bsum[i];
    sm[t] = s;
    __syncthreads();
    for (int off = 128; off > 0; off >>= 1) {
        if (t < off) sm[t] += sm[t + off];
        __syncthreads();
    }
    const int boff = sm[0];
    __syncthreads();
    // --- local inclusive scan of cnt
    const int i = b * 256 + t;
    const int v = (i < n) ? cnt[i] : 0;
    sm[t] = v;
    __syncthreads();
    for (int off = 1; off < 256; off <<= 1) {
        int u = (t >= off) ? sm[t - off] : 0;
        __syncthreads();
        sm[t] += u;
        __syncthreads();
    }
    const int incl = sm[t];
    const int excl = incl - v;
    if (i < n) rowptr[i] = boff + excl;
    if (i == n - 1) rowptr[n] = boff + incl;  // == E
}

__global__ void scatter_kernel(const int* __restrict__ src, const int* __restrict__ dst,
                               const int* __restrict__ rank, const int* __restrict__ rowptr,
                               int* __restrict__ esrc, int e) {
    const int t0 = blockIdx.x * (blockDim.x * 4) + threadIdx.x;
#pragma unroll
    for (int k = 0; k < 4; ++k) {
        const int j = t0 + k * 256;
        if (j < e) {
            const int d = dst[j];
            // plain cached store: slots rowptr[d]+rank coalesce in L2 (R4:
            // nt-store here = 64B partial-line HBM write per edge, 108MB)
            esrc[rowptr[d] + rank[j]] = src[j];
        }
    }
}

// ---------------------------------------------------------------------------
// MFMA GEMM (fp16 in, fp32 acc) + fused attention-logit epilogue.
// CONVA=true: A source is fp32 x, converted in-register (fuses conv_x;
// identical numerics: same cvt_pkrtz).
// ---------------------------------------------------------------------------
template <int FOUT, int H, bool CONVA>
__global__ __launch_bounds__(256) void gemm_mfma(const void* __restrict__ Xv,
                                                 const uint32* __restrict__ Wt,
                                                 const float* __restrict__ a_s,
                                                 const float* __restrict__ a_d,
                                                 float* __restrict__ alS,
                                                 float* __restrict__ alD,
                                                 uint32* __restrict__ Outh, int n) {
    constexpr int NT = FOUT / 16;            // 8 or 2 n-tiles
    const int wave = threadIdx.x >> 6;
    const int lane = threadIdx.x & 63;
    const int c = lane & 15;                 // D col / A load row / B col
    const int q = lane >> 4;                 // quad
    const int row0 = blockIdx.x * 128 + wave * 32;

    int r0 = row0 + c;
    int r1 = row0 + 16 + c;
    if (r0 >= n) r0 = n - 1;
    if (r1 >= n) r1 = n - 1;

    f32x4 acc[2][NT];
#pragma unroll
    for (int m = 0; m < 2; ++m)
#pragma unroll
        for (int nt = 0; nt < NT; ++nt) acc[m][nt] = (f32x4){0.f, 0.f, 0.f, 0.f};

    const uint4*  XU = (const uint4*)Xv;
    const float4* XF = (const float4*)Xv;
    const uint4*  WU = (const uint4*)Wt;

#pragma unroll
    for (int ks = 0; ks < 4; ++ks) {
        half8_t a0, a1;
        if constexpr (CONVA) {
            const float4 f0 = XF[(size_t)r0 * 32 + (ks * 4 + q) * 2];
            const float4 f1 = XF[(size_t)r0 * 32 + (ks * 4 + q) * 2 + 1];
            a0 = as_h8(make_uint4(packh2(f0.x, f0.y), packh2(f0.z, f0.w),
                                  packh2(f1.x, f1.y), packh2(f1.z, f1.w)));
            const float4 g0 = XF[(size_t)r1 * 32 + (ks * 4 + q) * 2];
            const float4 g1 = XF[(size_t)r1 * 32 + (ks * 4 + q) * 2 + 1];
            a1 = as_h8(make_uint4(packh2(g0.x, g0.y), packh2(g0.z, g0.w),
                                  packh2(g1.x, g1.y), packh2(g1.z, g1.w)));
        } else {
            a0 = as_h8(XU[(size_t)r0 * 16 + ks * 4 + q]);
            a1 = as_h8(XU[(size_t)r1 * 16 + ks * 4 + q]);
        }
#pragma unroll
        for (int nt = 0; nt < NT; ++nt) {
            const half8_t b = as_h8(WU[(nt * 16 + c) * 16 + ks * 4 + q]);
            acc[0][nt] = __builtin_amdgcn_mfma_f32_16x16x32_f16(a0, b, acc[0][nt], 0, 0, 0);
            acc[1][nt] = __builtin_amdgcn_mfma_f32_16x16x32_f16(a1, b, acc[1][nt], 0, 0, 0);
        }
    }

    // a_s/a_d values for my columns (flat [H*C] == flat col index)
    float asv[NT], adv[NT];
#pragma unroll
    for (int nt = 0; nt < NT; ++nt) {
        asv[nt] = a_s[c + 16 * nt];
        adv[nt] = a_d[c + 16 * nt];
    }

#pragma unroll
    for (int m = 0; m < 2; ++m) {
#pragma unroll
        for (int reg = 0; reg < 4; ++reg) {
            const int grow = row0 + m * 16 + q * 4 + reg;
            const bool ok = (grow < n);
            // ---- fused logits: per-head partial dot, reduce over 16-lane row group
            if constexpr (H == 4) {
                float ps[4], pd[4];
#pragma unroll
                for (int h = 0; h < 4; ++h) {
                    ps[h] = acc[m][2 * h][reg] * asv[2 * h] + acc[m][2 * h + 1][reg] * asv[2 * h + 1];
                    pd[h] = acc[m][2 * h][reg] * adv[2 * h] + acc[m][2 * h + 1][reg] * adv[2 * h + 1];
                }
#pragma unroll
                for (int off = 1; off < 16; off <<= 1) {
#pragma unroll
                    for (int h = 0; h < 4; ++h) {
                        ps[h] += __shfl_xor(ps[h], off);
                        pd[h] += __shfl_xor(pd[h], off);
                    }
                }
                if (c < 4 && ok) {
                    const float vs = (c == 0) ? ps[0] : (c == 1) ? ps[1] : (c == 2) ? ps[2] : ps[3];
                    const float vd = (c == 0) ? pd[0] : (c == 1) ? pd[1] : (c == 2) ? pd[2] : pd[3];
                    alS[(size_t)grow * 4 + c] = vs;
                    alD[(size_t)grow * 4 + c] = vd;
                }
            } else {
                float ps = acc[m][0][reg] * asv[0] + acc[m][1][reg] * asv[1];
                float pd = acc[m][0][reg] * adv[0] + acc[m][1][reg] * adv[1];
#pragma unroll
                for (int off = 1; off < 16; off <<= 1) {
                    ps += __shfl_xor(ps, off);
                    pd += __shfl_xor(pd, off);
                }
                if (c == 0 && ok) {
                    alS[grow] = ps;
                    alD[grow] = pd;
                }
            }
            // ---- fp16-packed C store: pair col c with c^1, even lanes write
#pragma unroll
            for (int nt = 0; nt < NT; ++nt) {
                const float v = acc[m][nt][reg];
                const float o = __shfl_xor(v, 1);
                if (((c & 1) == 0) && ok) {
                    Outh[(size_t)grow * (FOUT / 2) + nt * 8 + (c >> 1)] = packh2(v, o);
                }
            }
        }
    }
}

// ---------------------------------------------------------------------------
// wave-per-destination aggregation, single-phase / zero-LDS.
//   B16[d][F/2] = fp16( elu( (sum_e softmax(e)_e * h[src_e,:]) * A + B ) )
// Lane split: li = lane & (RU4-1) owns one uint4 (8 fp16 channels) of the row;
//             g  = lane / RU4 owns an edge slot.
// Plain cached accesses throughout (pinned control: ~75 µs, 226 MB FETCH —
// fabric floor for the 256B-granule random gather, measured R0-R3).
// NOTE: grid must be ceil(n/4); 4 destinations (waves) per block.
// ---------------------------------------------------------------------------
template <int H, int C>
__global__ __launch_bounds__(256) void gat_aggregate(
    const uint32* __restrict__ Hb,            // fp16-packed h, row = H*C/2 uints
    const int* __restrict__ rowptr, const int* __restrict__ esrc,
    const float* __restrict__ alS, const float* __restrict__ alD,
    const float* __restrict__ bnA, const float* __restrict__ bnB,
    uint32* __restrict__ B16, int n) {
    constexpr int F    = H * C;               // 128 or 32
    constexpr int RU4  = F / 8;               // uint4 per row: 16 or 4
    constexpr int SLOTS = 64 / RU4;           // edge slots: 4 or 16
    constexpr int UNROLL = 16 / SLOTS;        // 4 or 1  (16 edges per step)

    const int wave = threadIdx.x >> 6;
    const int lane = threadIdx.x & 63;
    int d = blockIdx.x * 4 + wave;
    if (d >= n) return;
    d = __builtin_amdgcn_readfirstlane(d);    // wave-uniform -> scalar addressing

    const int li = lane & (RU4 - 1);          // row quarter (8 channels: 8li..8li+7)
    const int g  = lane / RU4;                // edge slot
    const int head = (H == 4) ? (li >> 2) : 0;

    const float ald = alD[(size_t)d * H + head];
    const int beg = rowptr[d];
    const int end = rowptr[d + 1];
    const int endm1 = end - 1;

    float acc[8];
#pragma unroll
    for (int k = 0; k < 8; ++k) acc[k] = 0.f;
    float den = 0.f;

    const uint4* HbU4 = (const uint4*)Hb;

    for (int base = beg; base < end; base += 16) {
#pragma unroll
        for (int u = 0; u < UNROLL; ++u) {
            const int j  = base + u * SLOTS + g;
            const bool act = (j < end);
            const int jc = act ? j : endm1;          // clamp: stay in-bounds
            const int sj = esrc[jc];
            const float aw = (H == 4) ? alS[(size_t)sj * 4 + head] : alS[sj];
            float t = aw + ald;
            t = fmaxf(t, 0.2f * t);                  // leaky relu (slope 0.2)
            const float ex = act ? __expf(t) : 0.f;  // bounded logits: no max-sub
            den += ex;
            const uint4 v = HbU4[(size_t)sj * RU4 + li];
            acc[0] = fmaf(h_lo(v.x), ex, acc[0]);
            acc[1] = fmaf(h_hi(v.x), ex, acc[1]);
            acc[2] = fmaf(h_lo(v.y), ex, acc[2]);
            acc[3] = fmaf(h_hi(v.y), ex, acc[3]);
            acc[4] = fmaf(h_lo(v.z), ex, acc[4]);
            acc[5] = fmaf(h_hi(v.z), ex, acc[5]);
            acc[6] = fmaf(h_lo(v.w), ex, acc[6]);
            acc[7] = fmaf(h_hi(v.w), ex, acc[7]);
        }
    }

    // reduce across edge slots (xor over the g bits; li preserved)
#pragma unroll
    for (int off = RU4; off < 64; off <<= 1) {
#pragma unroll
        for (int k = 0; k < 8; ++k) acc[k] += __shfl_xor(acc[k], off);
        den += __shfl_xor(den, off);
    }

    if (lane < RU4) {
        const float inv = 1.f / (den + 1e-16f);
        const int c0 = 8 * li;
        const float4 A0 = *(const float4*)(bnA + c0);
        const float4 A1 = *(const float4*)(bnA + c0 + 4);
        const float4 B0 = *(const float4*)(bnB + c0);
        const float4 B1 = *(const float4*)(bnB + c0 + 4);
        const float As[8] = {A0.x, A0.y, A0.z, A0.w, A1.x, A1.y, A1.z, A1.w};
        const float Bs[8] = {B0.x, B0.y, B0.z, B0.w, B1.x, B1.y, B1.z, B1.w};
        float y[8];
#pragma unroll
        for (int k = 0; k < 8; ++k) {
            const float yy = acc[k] * inv * As[k] + Bs[k];
            y[k] = yy > 0.f ? yy : expm1f(yy);       // ELU
        }
        uint4 o;
        o.x = packh2(y[0], y[1]);
        o.y = packh2(y[2], y[3]);
        o.z = packh2(y[4], y[5]);
        o.w = packh2(y[6], y[7]);
        ((uint4*)B16)[(size_t)d * RU4 + li] = o;
    }
}

// ---------------------------------------------------------------------------
// classifier: out[n, 10] = fp16(H3)[n, 32] @ Wc[32, 10] + bc
// thread-per-node: row loaded once.
// ---------------------------------------------------------------------------
__global__ __launch_bounds__(256) void classifier_kernel(
    const uint32* __restrict__ H3, const float* __restrict__ Wc,
    const float* __restrict__ bc, float* __restrict__ out, int n) {
    const int ni = blockIdx.x * blockDim.x + threadIdx.x;
    if (ni >= n) return;
    const uint4* row = (const uint4*)(H3 + (size_t)ni * 16);
    float xf[32];
#pragma unroll
    for (int u = 0; u < 4; ++u) {
        const uint4 v = row[u];
        xf[u * 8 + 0] = h_lo(v.x); xf[u * 8 + 1] = h_hi(v.x);
        xf[u * 8 + 2] = h_lo(v.y); xf[u * 8 + 3] = h_hi(v.y);
        xf[u * 8 + 4] = h_lo(v.z); xf[u * 8 + 5] = h_hi(v.z);
        xf[u * 8 + 6] = h_lo(v.w); xf[u * 8 + 7] = h_hi(v.w);
    }
    float o[NCLS];
#pragma unroll
    for (int c = 0; c < NCLS; ++c) o[c] = bc[c];
#pragma unroll
    for (int u = 0; u < 32; ++u) {
#pragma unroll
        for (int c = 0; c < NCLS; ++c) o[c] = fmaf(xf[u], Wc[u * NCLS + c], o[c]);
    }
    float* orow = out + (size_t)ni * NCLS;
#pragma unroll
    for (int c = 0; c < NCLS; c += 2) {
        *(float2*)(orow + c) = make_float2(o[c], o[c + 1]);
    }
}

// ---------------------------------------------------------------------------
// launch
// ---------------------------------------------------------------------------
static inline char* align256(char* p) {
    return (char*)(((uintptr_t)p + 255) & ~(uintptr_t)255);
}

extern "C" void kernel_launch(void* const* d_in, const int* in_sizes, int n_in,
                              void* d_out, int out_size, void* d_ws, size_t ws_size,
                              hipStream_t stream) {
    const float* x  = (const float*)d_in[0];
    const int*   ei = (const int*)d_in[1];
    const int N = in_sizes[0] / FIN;
    const int E = in_sizes[1] / 2;
    const int* src = ei;
    const int* dst = ei + E;

    const float *W0 = (const float*)d_in[2],  *as0 = (const float*)d_in[3],
                *ad0 = (const float*)d_in[4], *b0 = (const float*)d_in[5],
                *g0 = (const float*)d_in[6],  *bt0 = (const float*)d_in[7],
                *m0 = (const float*)d_in[8],  *v0 = (const float*)d_in[9];
    const float *W1 = (const float*)d_in[10], *as1 = (const float*)d_in[11],
                *ad1 = (const float*)d_in[12],*b1 = (const float*)d_in[13],
                *g1 = (const float*)d_in[14], *bt1 = (const float*)d_in[15],
                *m1 = (const float*)d_in[16], *v1 = (const float*)d_in[17];
    const float *W2 = (const float*)d_in[18], *as2 = (const float*)d_in[19],
                *ad2 = (const float*)d_in[20],*b2 = (const float*)d_in[21],
                *g2 = (const float*)d_in[22], *bt2 = (const float*)d_in[23],
                *m2 = (const float*)d_in[24], *v2 = (const float*)d_in[25];
    const float *Wc = (const float*)d_in[26], *bc = (const float*)d_in[27];
    float* out = (float*)d_out;

    // workspace carve
    char* p = (char*)d_ws;
    uint32* Ht  = (uint32*)p;   p = align256(p + (size_t)N * 64 * 4);    // gemm out fp16
    uint32* B16 = (uint32*)p;   p = align256(p + (size_t)N * 64 * 4);    // layer act fp16
    uint32* Wt0 = (uint32*)p;   p = align256(p + 8192 * 4);
    uint32* Wt1 = (uint32*)p;   p = align256(p + 8192 * 4);
    uint32* Wt2 = (uint32*)p;   p = align256(p + 2048 * 4);
    float* alS = (float*)p;     p = align256(p + (size_t)N * NHEADS * 4);
    float* alD = (float*)p;     p = align256(p + (size_t)N * NHEADS * 4);
    int* cnt = (int*)p;         p = align256(p + (size_t)N * 4);
    int* rowptr = (int*)p;      p = align256(p + (size_t)(N + 1) * 4);
    int* rank = (int*)p;        p = align256(p + (size_t)E * 4);
    int* esrc = (int*)p;        p = align256(p + (size_t)E * 4);
    int* bsum = (int*)p;        p = align256(p + 512 * 4);
    float* bnA = (float*)p;     p = align256(p + 288 * 4);
    float* bnB = (float*)p;     p = align256(p + 288 * 4);
    (void)ws_size; (void)n_in; (void)out_size;

    const int NB = (N + 255) / 256;
    const int EB4 = (E + 1023) / 1024;   // 4 edges/thread kernels

    // ---- setup (zero cnt + weight conversion + BN fold, one launch) ----
    setup_kernel<<<NB, 256, 0, stream>>>(cnt, N, W0, W1, W2, Wt0, Wt1, Wt2,
                                         b0, g0, bt0, m0, v0,
                                         b1, g1, bt1, m1, v1,
                                         b2, g2, bt2, m2, v2, bnA, bnB);

    // ---- CSR build (once; shared by all 3 layers) ----
    hist_rank_kernel<<<EB4, 256, 0, stream>>>(dst, cnt, rank, E);
    scan_block_sums<<<NB, 256, 0, stream>>>(cnt, bsum, N);
    scan_final<<<NB, 256, 0, stream>>>(cnt, bsum, rowptr, N);
    scatter_kernel<<<EB4, 256, 0, stream>>>(src, dst, rank, rowptr, esrc, E);

    const int GB = (N + 127) / 128;
    const int AB = (N + 3) / 4;          // aggregate blocks: 4 dst per block

    // ---- layer 0 (fp32 x converted in-register in the GEMM A-path) ----
    gemm_mfma<128, 4, true><<<GB, 256, 0, stream>>>(x, Wt0, as0, ad0, alS, alD, Ht, N);
    gat_aggregate<4, 32><<<AB, 256, 0, stream>>>(Ht, rowptr, esrc, alS, alD,
                                                 bnA, bnB, B16, N);
    // ---- layer 1 ----
    gemm_mfma<128, 4, false><<<GB, 256, 0, stream>>>(B16, Wt1, as1, ad1, alS, alD, Ht, N);
    gat_aggregate<4, 32><<<AB, 256, 0, stream>>>(Ht, rowptr, esrc, alS, alD,
                                                 bnA + 128, bnB + 128, B16, N);
    // ---- layer 2 (single head, C=32) ----
    gemm_mfma<32, 1, false><<<GB, 256, 0, stream>>>(B16, Wt2, as2, ad2, alS, alD, Ht, N);
    gat_aggregate<1, 32><<<AB, 256, 0, stream>>>(Ht, rowptr, esrc, alS, alD,
                                                 bnA + 256, bnB + 256, B16, N);
    // ---- classifier ----
    classifier_kernel<<<(N + 255) / 256, 256, 0, stream>>>(B16, Wc, bc, out, N);
}